// Round 8
// baseline (580.239 us; speedup 1.0000x reference)
//
#include <hip/hip_runtime.h>
#include <hip/hip_bf16.h>
#include <stdint.h>

// y = x @ quant(w).T + bias
//   x: (8192, 4096) fp32   w: (4096, 4096) fp32 (OUT, IN)   bias: (4096,) fp32
// R10: single-phase K-tile. All 24 ds_read_b128 + 4 stage units + 64-MFMA
// burst + VM0 + ONE fenced barrier per K-tile (was 4 phases / 8 barriers /
// 3 waits). No explicit lgkmcnt: compiler fine-grained waits let the MFMA
// burst start after the first frags land; remaining reads drain under it.
// Pre-pass unchanged from R9.

using short8  = __attribute__((ext_vector_type(8))) short;   // 8 bf16 = 4 VGPR
using float4v = __attribute__((ext_vector_type(4))) float;   // 4 fp32

// ---------- helpers ----------

__device__ __forceinline__ unsigned short f2bf(float f) {
    union { float f; uint32_t u; } v; v.f = f;
    uint32_t u = v.u;
    u += 0x7fffu + ((u >> 16) & 1u);   // RNE
    return (unsigned short)(u >> 16);
}

__device__ __forceinline__ void gload_lds16(const unsigned short* g, unsigned short* l) {
    __builtin_amdgcn_global_load_lds(
        (const __attribute__((address_space(1))) void*)g,
        (__attribute__((address_space(3))) void*)l,
        16, 0, 0);
}

// ---------- pre-pass 1: absmax(w) ----------

#define AMB 1024   // absmax blocks

__global__ __launch_bounds__(256) void absmax_kernel(
        const float4* __restrict__ w4, int n4, unsigned int* __restrict__ amax_out) {
    float m = 0.f;
    for (int i = blockIdx.x * blockDim.x + threadIdx.x; i < n4; i += AMB * blockDim.x) {
        float4 v = w4[i];
        m = fmaxf(m, fmaxf(fmaxf(fabsf(v.x), fabsf(v.y)), fmaxf(fabsf(v.z), fabsf(v.w))));
    }
    #pragma unroll
    for (int off = 32; off > 0; off >>= 1)
        m = fmaxf(m, __shfl_down(m, off, 64));
    __shared__ float smax[4];
    int lane = threadIdx.x & 63, wv = threadIdx.x >> 6;
    if (lane == 0) smax[wv] = m;
    __syncthreads();
    if (threadIdx.x == 0) {
        float bm = fmaxf(fmaxf(smax[0], smax[1]), fmaxf(smax[2], smax[3]));
        atomicMax(amax_out, __float_as_uint(bm));  // vals >= 0: uint order == float order
    }
}

// ---------- pre-pass 2 (fused): cvt x->bf16 + quant/dequant w->bf16 ----------

__device__ __forceinline__ uint32_t pack2bf(float lo, float hi) {
    return (uint32_t)f2bf(lo) | ((uint32_t)f2bf(hi) << 16);
}

__global__ __launch_bounds__(256) void cvtquant_kernel(
        const float4* __restrict__ x,  uint4* __restrict__ xb, int xn8,
        const float4* __restrict__ w,  uint4* __restrict__ wq, int wn8,
        int xblocks,
        const unsigned int* __restrict__ amax_bits) {
    if ((int)blockIdx.x < xblocks) {
        for (int i = blockIdx.x * blockDim.x + threadIdx.x; i < xn8;
             i += xblocks * blockDim.x) {
            float4 a = x[2 * i], b = x[2 * i + 1];
            uint4 o;
            o.x = pack2bf(a.x, a.y); o.y = pack2bf(a.z, a.w);
            o.z = pack2bf(b.x, b.y); o.w = pack2bf(b.z, b.w);
            xb[i] = o;
        }
    } else {
        const int qb = gridDim.x - xblocks;
        const float amax  = __uint_as_float(*amax_bits);
        const float scale = amax / 127.0f;
        const float inv   = 1.0f / scale;
        for (int i = ((int)blockIdx.x - xblocks) * blockDim.x + threadIdx.x; i < wn8;
             i += qb * blockDim.x) {
            float4 a = w[2 * i], b = w[2 * i + 1];
            float q0 = fminf(fmaxf(rintf(a.x * inv), -127.f), 127.f) * scale;
            float q1 = fminf(fmaxf(rintf(a.y * inv), -127.f), 127.f) * scale;
            float q2 = fminf(fmaxf(rintf(a.z * inv), -127.f), 127.f) * scale;
            float q3 = fminf(fmaxf(rintf(a.w * inv), -127.f), 127.f) * scale;
            float q4 = fminf(fmaxf(rintf(b.x * inv), -127.f), 127.f) * scale;
            float q5 = fminf(fmaxf(rintf(b.y * inv), -127.f), 127.f) * scale;
            float q6 = fminf(fmaxf(rintf(b.z * inv), -127.f), 127.f) * scale;
            float q7 = fminf(fmaxf(rintf(b.w * inv), -127.f), 127.f) * scale;
            uint4 o;
            o.x = pack2bf(q0, q1); o.y = pack2bf(q2, q3);
            o.z = pack2bf(q4, q5); o.w = pack2bf(q6, q7);
            wq[i] = o;
        }
    }
}

// ---------- GEMM: C(MxN) = A(MxK) * B(NxK)^T + bias ----------
// 256x256 tile, BK=64, 512 threads (2x4 waves), per-wave 128x64 output
// (acc[8][4] of 16x16 frags). LDS: 2 buffers x (A[2 regions][128][64] +
// B likewise) bf16 = 128 KB. Chunk-XOR swizzle (source pre-swizzled, reads
// apply same XOR).
//
// Single-phase K-tile T (buf b = T&1):
//   RD aLo(8 b128), bLo(4)           <- Q00 operands first
//   STAGE all 4 units of T+1 -> b^1  (8 gload_lds; skip on last tile)
//   MMA Q00(16)  | RD bHi(4)
//   MMA Q01(16)  | RD aHi(8)
//   MMA Q10(16), Q11(16)
//   VM0 (naked; stages issued ~2500 cyc earlier -> ~free)
//   BARF (single fenced barrier per K-tile)
// Hazards: every ds_read has an MFMA consumer before the tile-end barrier
// (reads retired at BARF -> T+1's stages can't clobber unread data);
// stages target the opposite buffer; VM0+BARF makes T+1's data block-wide
// visible before its reads.

#define HFE  8192     // elements per 128x64 region
#define BUFE 16384    // elements per buffer (A or B): 2 regions

#define VM0  asm volatile("s_waitcnt vmcnt(0)")
#define VMNONE ((void)0)
// single correctness-anchor barrier per K-tile: full fence
#define BARF do { asm volatile("" ::: "memory"); __builtin_amdgcn_s_barrier(); \
                  asm volatile("" ::: "memory"); } while (0)

__global__ __launch_bounds__(512, 2) void gemm_bt(
    const unsigned short* __restrict__ A,   // M x K bf16
    const unsigned short* __restrict__ B,   // N x K bf16
    const float* __restrict__ bias,
    float* __restrict__ C,                  // M x N fp32
    int M, int N, int K)
{
    __shared__ __align__(16) unsigned short As[2 * BUFE];   // 64 KB
    __shared__ __align__(16) unsigned short Bs[2 * BUFE];   // 64 KB

    const int tid = threadIdx.x;
    const int l   = tid & 63;
    const int w   = tid >> 6;        // wave 0..7
    const int wm  = w >> 2;          // 0..1 : which 128-row A region this wave reads
    const int wn  = w & 3;           // 0..3 : which 64-row B slice

    // bijective XCD swizzle of flattened block id (nwg % 8 == 0 here)
    const int nbx = gridDim.x;
    int flat = blockIdx.y * nbx + blockIdx.x;
    const int cpx = (nbx * gridDim.y) >> 3;
    flat = (flat & 7) * cpx + (flat >> 3);
    const int bm = (flat / nbx) * 256;
    const int bn = (flat % nbx) * 256;

    // --- staging constants ---
    const int lq  = l >> 3;                         // 0..7
    const int gch = (l & 7) ^ (lq & 7);             // inverse-swizzled source chunk

    const int a_grow = (w >> 2) * 128 + (w & 3) * 16 + lq;          // global tile row
    const int a_base = (w >> 2) * HFE + (w & 3) * 1024;             // LDS elems (uniform)
    const int b_grow = (w >> 2) * 128 + ((w >> 1) & 1) * 64 + (w & 1) * 16 + lq;
    const int b_base = (w >> 2) * HFE + ((w >> 1) & 1) * 4096 + (w & 1) * 1024;

    const unsigned short* aS0 = A + (size_t)(bm + a_grow) * K + gch * 8;
    const unsigned short* bS0 = B + (size_t)(bn + b_grow) * K + gch * 8;

#define STAGE_AU(NB, U, KT) do { \
    const unsigned short* s_ = aS0 + (size_t)(U) * 64 * K + (size_t)(KT) * 64; \
    unsigned short* d_ = As + (NB) * BUFE + a_base + (U) * 4096; \
    gload_lds16(s_, d_); gload_lds16(s_ + 8 * (size_t)K, d_ + 512); } while (0)
#define STAGE_BU(NB, U, KT) do { \
    const unsigned short* s_ = bS0 + (size_t)(U) * 32 * K + (size_t)(KT) * 64; \
    unsigned short* d_ = Bs + (NB) * BUFE + b_base + (U) * 2048; \
    gload_lds16(s_, d_); gload_lds16(s_ + 8 * (size_t)K, d_ + 512); } while (0)
#define STAGE_ALL(NB, KT) do { \
    STAGE_AU(NB, 0, KT); STAGE_BU(NB, 0, KT); \
    STAGE_BU(NB, 1, KT); STAGE_AU(NB, 1, KT); } while (0)

    // --- fragment read: row r = frag*16 + (l&15); chunk ((ks<<2)|quad) ^ (r&7) ---
    const int lr   = l & 15;
    const int quad = l >> 4;
    const int c0   = (quad ^ (l & 7)) * 8;          // ks=0 element offset within row
    const int c1   = ((quad ^ (l & 7)) ^ 4) * 8;    // ks=1
    const unsigned short* paB = As + wm * HFE + lr * 64;
    const unsigned short* pbB = Bs + (wn >> 1) * HFE + (wn & 1) * 4096 + lr * 64;

    float4v acc[8][4];
    const float4v zero = {0.f, 0.f, 0.f, 0.f};
    #pragma unroll
    for (int i = 0; i < 8; i++)
        #pragma unroll
        for (int j = 0; j < 4; j++) acc[i][j] = zero;

    short8 aLo[4][2], aHi[4][2], bLo[2][2], bHi[2][2];

// read A frags (MH half: 0 -> rows[0,64), 1 -> rows[64,128))
#define RD_A(DST, PA, MH) do { _Pragma("unroll") \
    for (int i_ = 0; i_ < 4; i_++) { \
        DST[i_][0] = *(const short8*)((PA) + ((MH) * 4 + i_) * 1024 + c0); \
        DST[i_][1] = *(const short8*)((PA) + ((MH) * 4 + i_) * 1024 + c1); } } while (0)
// read B frags (NH half: 0 -> rows[0,32), 1 -> rows[32,64))
#define RD_B(DST, PB, NH) do { _Pragma("unroll") \
    for (int j_ = 0; j_ < 2; j_++) { \
        DST[j_][0] = *(const short8*)((PB) + ((NH) * 2 + j_) * 1024 + c0); \
        DST[j_][1] = *(const short8*)((PB) + ((NH) * 2 + j_) * 1024 + c1); } } while (0)
#define MMA_Q(AF, BF, MH, NH) do { \
    __builtin_amdgcn_s_setprio(1); \
    _Pragma("unroll") for (int i_ = 0; i_ < 4; i_++) \
    _Pragma("unroll") for (int j_ = 0; j_ < 2; j_++) { \
        acc[(MH)*4+i_][(NH)*2+j_] = __builtin_amdgcn_mfma_f32_16x16x32_bf16( \
            AF[i_][0], BF[j_][0], acc[(MH)*4+i_][(NH)*2+j_], 0, 0, 0); \
        acc[(MH)*4+i_][(NH)*2+j_] = __builtin_amdgcn_mfma_f32_16x16x32_bf16( \
            AF[i_][1], BF[j_][1], acc[(MH)*4+i_][(NH)*2+j_], 0, 0, 0); } \
    __builtin_amdgcn_s_setprio(0); } while (0)

// One K-tile, single phase, one barrier.
#define GEMM_TILE(CB_, PRE, ENDW) do { \
    const unsigned short* pa_ = paB + (CB_) * BUFE; \
    const unsigned short* pb_ = pbB + (CB_) * BUFE; \
    RD_A(aLo, pa_, 0); RD_B(bLo, pb_, 0); \
    if (PRE) STAGE_ALL((CB_) ^ 1, kt + 1); \
    MMA_Q(aLo, bLo, 0, 0); \
    RD_B(bHi, pb_, 1); \
    MMA_Q(aLo, bHi, 0, 1); \
    RD_A(aHi, pa_, 1); \
    MMA_Q(aHi, bLo, 1, 0); \
    MMA_Q(aHi, bHi, 1, 1); \
    ENDW; \
    BARF; \
} while (0)

    // prologue: stage tile 0, drain, sync
    STAGE_ALL(0, 0);
    VM0; BARF;

    const int NT = K >> 6;                 // = 64
    int kt = 0, cb = 0;
    for (; kt < NT - 1; ++kt, cb ^= 1)
        GEMM_TILE(cb, 1, VM0);
    GEMM_TILE(cb, 0, VMNONE);              // last tile: nothing in flight

    // --- epilogue: C/D layout col=lane&15, row=(lane>>4)*4+reg ---
    #pragma unroll
    for (int j = 0; j < 4; j++) {
        const int gc = bn + wn * 64 + j * 16 + lr;
        const float bs = bias[gc];
        #pragma unroll
        for (int i = 0; i < 8; i++) {
            const int gr = bm + wm * 128 + i * 16 + quad * 4;
            float* cp = C + (size_t)gr * N + gc;
            #pragma unroll
            for (int r = 0; r < 4; r++)
                cp[(size_t)r * N] = acc[i][j][r] + bs;
        }
    }
}

// ---------- launch ----------

extern "C" void kernel_launch(void* const* d_in, const int* in_sizes, int n_in,
                              void* d_out, int out_size, void* d_ws, size_t ws_size,
                              hipStream_t stream) {
    const float* x    = (const float*)d_in[0];   // (M, K)
    const float* w    = (const float*)d_in[1];   // (N, K)
    const float* bias = (const float*)d_in[2];   // (N,)
    float* out = (float*)d_out;

    const int N = 4096, K = 4096;
    const int M = in_sizes[0] / K;               // 8192

    // workspace: [256B amax | wq bf16 N*K | xb bf16 chunk]
    const size_t wq_off   = 256;
    const size_t wq_bytes = (size_t)N * K * 2;
    unsigned int*   amax = (unsigned int*)d_ws;
    unsigned short* wq   = (unsigned short*)((char*)d_ws + wq_off);
    unsigned short* xb   = (unsigned short*)((char*)d_ws + wq_off + wq_bytes);

    size_t avail = (ws_size > wq_off + wq_bytes) ? ws_size - wq_off - wq_bytes : 0;
    int nch = 1;
    while (nch < 32 && (size_t)(M / nch) * K * 2 > avail) nch <<= 1;
    const int crows = M / nch;                   // multiple of 256 for M=8192, nch<=32

    hipMemsetAsync(d_ws, 0, 256, stream);

    // pre-pass: absmax(w), then fused {cvt x | quant w}
    absmax_kernel<<<AMB, 256, 0, stream>>>((const float4*)w, (N * K) / 4, amax);

    if (nch == 1) {
        cvtquant_kernel<<<2048, 256, 0, stream>>>(
            (const float4*)x, (uint4*)xb, (M * K) / 8,
            (const float4*)w, (uint4*)wq, (N * K) / 8,
            1365, amax);
        dim3 grid(N / 256, M / 256);
        gemm_bt<<<grid, 512, 0, stream>>>(xb, wq, bias, out, M, N, K);
    } else {
        cvtquant_kernel<<<704, 256, 0, stream>>>(
            nullptr, nullptr, 0,
            (const float4*)w, (uint4*)wq, (N * K) / 8,
            0, amax);
        for (int c = 0; c < nch; c++) {
            const float* xc = x + (size_t)c * crows * K;
            cvtquant_kernel<<<1344, 256, 0, stream>>>(
                (const float4*)xc, (uint4*)xb, (crows * K) / 8,
                nullptr, nullptr, 0,
                1344, amax);
            dim3 grid(N / 256, crows / 256);
            gemm_bt<<<grid, 512, 0, stream>>>(xb, wq, bias, out + (size_t)c * crows * N,
                                              crows, N, K);
        }
    }
}